// Round 3
// baseline (463.089 us; speedup 1.0000x reference)
//
#include <hip/hip_runtime.h>

typedef _Float16 f16;
typedef f16 half8 __attribute__((ext_vector_type(8)));
typedef float f32x4 __attribute__((ext_vector_type(4)));

#define MFMA16(a, b, c) __builtin_amdgcn_mfma_f32_16x16x32_f16((a), (b), (c), 0, 0, 0)

static constexpr int B = 8, C = 256, CI = 128, N = 6272, M = 1568, MP = 1600;

// f16-element offsets into workspace (~45 MB). Y aliases phiF (phiF dead after k_pool).
static constexpr size_t oQ  = 0;                         // [B][N][CI]  theta
static constexpr size_t oPF = oQ  + (size_t)B * N * CI;  // [B][N][CI]  phi full-res; later Y
static constexpr size_t oGF = oPF + (size_t)B * N * CI;  // [B][N][CI]  g full-res
static constexpr size_t oPP = oGF + (size_t)B * N * CI;  // [B][MP][CI] phi pooled (K), pad zeroed
static constexpr size_t oGT = oPP + (size_t)B * MP * CI; // [B][CI][MP] g pooled transposed (V), pad zeroed
static constexpr size_t oW  = oGT + (size_t)B * MP * CI; // 4*32768 f16 weights: theta|phi|g|W

static __device__ __forceinline__ half8 hmax8(half8 a, half8 b) {
    half8 r;
#pragma unroll
    for (int j = 0; j < 8; j++) r[j] = a[j] > b[j] ? a[j] : b[j];
    return r;
}

// max across the 16 consecutive lanes of a DPP row-group
static __device__ __forceinline__ float rowmax16(float x) {
    int t;
    t = __builtin_amdgcn_update_dpp(__float_as_int(x), __float_as_int(x), 0x121, 0xF, 0xF, false);
    x = fmaxf(x, __int_as_float(t));
    t = __builtin_amdgcn_update_dpp(__float_as_int(x), __float_as_int(x), 0x122, 0xF, 0xF, false);
    x = fmaxf(x, __int_as_float(t));
    t = __builtin_amdgcn_update_dpp(__float_as_int(x), __float_as_int(x), 0x124, 0xF, 0xF, false);
    x = fmaxf(x, __int_as_float(t));
    t = __builtin_amdgcn_update_dpp(__float_as_int(x), __float_as_int(x), 0x128, 0xF, 0xF, false);
    x = fmaxf(x, __int_as_float(t));
    return x;
}

// ---------------- weight cast fp32 -> f16 (theta|phi|g|W contiguous) ----------------
__global__ void k_prep(const float* tw, const float* pw, const float* gw,
                       const float* Ww, f16* dst) {
    int i = blockIdx.x * 256 + threadIdx.x;   // 0..131071
    int s = i >> 15, j = i & 32767;
    float v;
    if (s == 0) v = tw[j];
    else if (s == 1) v = pw[j];
    else if (s == 2) v = gw[j];
    else v = Ww[j];
    dst[i] = (f16)v;
}

// ---------------- fused 3-way projection: reads x[b][c][n] fp32 directly ----------------
// out{Q,phiF,gF}[b][n][ci] = sum_c x[b][c][n] * w[ci][c] + bias[ci]
__global__ __launch_bounds__(256) void k_projf(const float* __restrict__ x,
                                               const f16* __restrict__ w16,
                                               const float* __restrict__ tb,
                                               const float* __restrict__ pb,
                                               const float* __restrict__ gb,
                                               f16* __restrict__ Q,
                                               f16* __restrict__ phiF,
                                               f16* __restrict__ gF) {
    __shared__ f16 xs[64 * 72];    // [64 n][64 c] pad 8 (staged transposed + cvt)
    __shared__ f16 ws[384 * 72];   // [384 ci][64 c] pad 8
    int b = blockIdx.y, n0 = blockIdx.x * 64;
    int tid = threadIdx.x, w = tid >> 6, lane = tid & 63, ln = lane & 15, quad = lane >> 4;
    int nl = tid & 63, cg = tid >> 6;   // staging role: thread owns n=n0+nl, c-group cg*16

    f32x4 acc[4][6];
#pragma unroll
    for (int nt = 0; nt < 4; nt++)
#pragma unroll
        for (int cb = 0; cb < 6; cb++) acc[nt][cb] = (f32x4){0.f, 0.f, 0.f, 0.f};

    for (int kc = 0; kc < 4; kc++) {
        // stage weights: 384 rows x 64 c
#pragma unroll
        for (int i = 0; i < 12; i++) {
            int qq = tid + i * 256;          // 0..3071
            int row = qq >> 3, coff = (qq & 7) * 8;
            *(int4*)&ws[row * 72 + coff] =
                *(const int4*)&w16[(size_t)row * C + kc * 64 + coff];
        }
        // stage x-tile transposed: thread reads 16 c's (coalesced along n per c)
        {
            half8 h0, h1;
#pragma unroll
            for (int j = 0; j < 8; j++)
                h0[j] = (f16)x[(size_t)(b * C + kc * 64 + cg * 16 + j) * N + n0 + nl];
#pragma unroll
            for (int j = 0; j < 8; j++)
                h1[j] = (f16)x[(size_t)(b * C + kc * 64 + cg * 16 + 8 + j) * N + n0 + nl];
            *(half8*)&xs[nl * 72 + cg * 16] = h0;
            *(half8*)&xs[nl * 72 + cg * 16 + 8] = h1;
        }
        __syncthreads();
#pragma unroll
        for (int ks = 0; ks < 2; ks++) {
            half8 af[4];
#pragma unroll
            for (int nt = 0; nt < 4; nt++)
                af[nt] = *(const half8*)&xs[(nt * 16 + ln) * 72 + ks * 32 + quad * 8];
#pragma unroll
            for (int cb = 0; cb < 6; cb++) {
                half8 bf = *(const half8*)&ws[(w * 96 + cb * 16 + ln) * 72 + ks * 32 + quad * 8];
#pragma unroll
                for (int nt = 0; nt < 4; nt++) acc[nt][cb] = MFMA16(af[nt], bf, acc[nt][cb]);
            }
        }
        __syncthreads();
    }
#pragma unroll
    for (int cb = 0; cb < 6; cb++) {
        int cig = w * 96 + cb * 16;          // tile base, wave-uniform; never crosses a 128-boundary
        int sel = cig >> 7, cil = (cig & 127) + ln;
        const float* bp = sel == 0 ? tb : (sel == 1 ? pb : gb);
        f16* outp = sel == 0 ? Q : (sel == 1 ? phiF : gF);
        float bv = bp[cil];
#pragma unroll
        for (int nt = 0; nt < 4; nt++) {
#pragma unroll
            for (int r = 0; r < 4; r++) {
                int n = n0 + nt * 16 + quad * 4 + r;
                outp[(size_t)(b * N + n) * CI + cil] = (f16)(acc[nt][cb][r] + bv);
            }
        }
    }
}

// ---------------- 2x2 spatial maxpool; K as [m][ci], V as [ci][m] (coalesced via LDS transpose) ----
__global__ __launch_bounds__(256) void k_pool(const f16* __restrict__ phiF, const f16* __restrict__ gF,
                                              f16* __restrict__ phiP, f16* __restrict__ gPT) {
    __shared__ f16 gt[128 * 72];   // [128 ci][64 m] pad 8
    int b = blockIdx.y, mt = blockIdx.x;   // mt 0..24 over MP=1600
    int tid = threadIdx.x;
#pragma unroll
    for (int i = 0; i < 4; i++) {
        int qq = tid + i * 256;            // 0..1023
        int ml = qq >> 4, coff = (qq & 15) * 8;
        int m = mt * 64 + ml;
        half8 pv, gv;
        if (m < M) {
            int t = m / 196, rr = m % 196, hp = rr / 14, wp = rr % 14;
            int nb = t * 784 + hp * 56 + wp * 2;
            size_t base = ((size_t)(b * N) + nb) * CI + coff;
            half8 p0 = *(const half8*)&phiF[base];
            half8 p1 = *(const half8*)&phiF[base + CI];
            half8 p2 = *(const half8*)&phiF[base + 28 * CI];
            half8 p3 = *(const half8*)&phiF[base + 29 * CI];
            pv = hmax8(hmax8(p0, p1), hmax8(p2, p3));
            half8 g0 = *(const half8*)&gF[base];
            half8 g1 = *(const half8*)&gF[base + CI];
            half8 g2 = *(const half8*)&gF[base + 28 * CI];
            half8 g3 = *(const half8*)&gF[base + 29 * CI];
            gv = hmax8(hmax8(g0, g1), hmax8(g2, g3));
        } else {
#pragma unroll
            for (int j = 0; j < 8; j++) { pv[j] = (f16)0.f; gv[j] = (f16)0.f; }
        }
        *(half8*)&phiP[((size_t)b * MP + m) * CI + coff] = pv;
#pragma unroll
        for (int j = 0; j < 8; j++) gt[(coff + j) * 72 + ml] = gv[j];
    }
    __syncthreads();
#pragma unroll
    for (int i = 0; i < 4; i++) {
        int qq = tid + i * 256;
        int ci = qq >> 3, moff = (qq & 7) * 8;
        *(int4*)&gPT[((size_t)(b * CI) + ci) * MP + mt * 64 + moff] = *(const int4*)&gt[ci * 72 + moff];
    }
}

// ---------------- flash attention: 2-wave blocks, q=64/block, 3 blocks/CU ----------------
__global__ __launch_bounds__(128, 2) void k_attn(const f16* __restrict__ q,
                                                 const f16* __restrict__ kk,
                                                 const f16* __restrict__ v,
                                                 f16* __restrict__ y) {
    __shared__ f16 Ks[64 * 136];     // [64 m][128 d] pad 8
    __shared__ f16 Vs[128 * 72];     // [128 ci][64 m] pad 8
    __shared__ f16 Ps[2 * 32 * 72];  // per-wave [32 q][64 m] pad 8
    int b = blockIdx.y, n0 = blockIdx.x * 64;
    int tid = threadIdx.x, w = tid >> 6, lane = tid & 63, ln = lane & 15, quad = lane >> 4;
    int wq = n0 + w * 32;
    f16* Pw = &Ps[w * 32 * 72];

    // Q fragments in registers, pre-scaled by log2(e) so softmax is pure exp2
    half8 qf[2][4];
#pragma unroll
    for (int qt = 0; qt < 2; qt++)
#pragma unroll
        for (int ks = 0; ks < 4; ks++) {
            qf[qt][ks] = *(const half8*)&q[(size_t)(b * N + wq + qt * 16 + ln) * CI + ks * 32 + quad * 8];
#pragma unroll
            for (int j = 0; j < 8; j++) qf[qt][ks][j] *= (f16)1.4426950408889634f;
        }

    f32x4 O[2][8], Osum[2];
#pragma unroll
    for (int qt = 0; qt < 2; qt++) {
        Osum[qt] = (f32x4){0.f, 0.f, 0.f, 0.f};
#pragma unroll
        for (int cb = 0; cb < 8; cb++) O[qt][cb] = (f32x4){0.f, 0.f, 0.f, 0.f};
    }
    float mi[2][4] = {{-1e30f, -1e30f, -1e30f, -1e30f}, {-1e30f, -1e30f, -1e30f, -1e30f}};

    for (int mc = 0; mc < 25; mc++) {
        // ---- stage K (16KB) + V (16KB) ----
#pragma unroll
        for (int i = 0; i < 8; i++) {
            int qq = tid + i * 128;
            int kr = qq >> 4, kc = (qq & 15) * 8;
            *(int4*)&Ks[kr * 136 + kc] = *(const int4*)&kk[((size_t)b * MP + mc * 64 + kr) * CI + kc];
            int vr = qq >> 3, vc = (qq & 7) * 8;
            *(int4*)&Vs[vr * 72 + vc] = *(const int4*)&v[((size_t)(b * CI) + vr) * MP + mc * 64 + vc];
        }
        __syncthreads();

        // ---- QK^T: 32 MFMA, each K fragment feeds both q-tiles ----
        f32x4 S[2][4];
#pragma unroll
        for (int mt = 0; mt < 4; mt++) {
            f32x4 s0 = (f32x4){0.f, 0.f, 0.f, 0.f}, s1 = (f32x4){0.f, 0.f, 0.f, 0.f};
#pragma unroll
            for (int ks = 0; ks < 4; ks++) {
                half8 kb = *(const half8*)&Ks[(mt * 16 + ln) * 136 + ks * 32 + quad * 8];
                s0 = MFMA16(qf[0][ks], kb, s0);
                s1 = MFMA16(qf[1][ks], kb, s1);
            }
            S[0][mt] = s0; S[1][mt] = s1;
        }

        // ---- online softmax (log2 domain): DPP row-max, MFMA rowsum ----
#pragma unroll
        for (int qt = 0; qt < 2; qt++)
#pragma unroll
            for (int r = 0; r < 4; r++) {
                float vm = fmaxf(fmaxf(S[qt][0][r], S[qt][1][r]), fmaxf(S[qt][2][r], S[qt][3][r]));
                vm = rowmax16(vm);
                float mnew = fmaxf(mi[qt][r], vm);
                float alpha = __builtin_amdgcn_exp2f(mi[qt][r] - mnew);
                mi[qt][r] = mnew;
#pragma unroll
                for (int mt = 0; mt < 4; mt++) {
                    float p = __builtin_amdgcn_exp2f(S[qt][mt][r] - mnew);
                    Pw[(qt * 16 + quad * 4 + r) * 72 + mt * 16 + ln] = (f16)p;
                }
#pragma unroll
                for (int cb = 0; cb < 8; cb++) O[qt][cb][r] *= alpha;
                Osum[qt][r] *= alpha;
            }

        // ---- PV + ones-column rowsum ----
#pragma unroll
        for (int ks = 0; ks < 2; ks++) {
            half8 a0 = *(const half8*)&Pw[ln * 72 + ks * 32 + quad * 8];
            half8 a1 = *(const half8*)&Pw[(16 + ln) * 72 + ks * 32 + quad * 8];
            f16 ov = (mc * 64 + ks * 32 < M) ? (f16)1.0f : (f16)0.0f;  // mask pad cols
            half8 on;
#pragma unroll
            for (int j = 0; j < 8; j++) on[j] = ov;
#pragma unroll
            for (int cb = 0; cb < 8; cb++) {
                half8 bv = *(const half8*)&Vs[(cb * 16 + ln) * 72 + ks * 32 + quad * 8];
                O[0][cb] = MFMA16(a0, bv, O[0][cb]);
                O[1][cb] = MFMA16(a1, bv, O[1][cb]);
            }
            Osum[0] = MFMA16(a0, on, Osum[0]);
            Osum[1] = MFMA16(a1, on, Osum[1]);
        }
        __syncthreads();
    }

#pragma unroll
    for (int qt = 0; qt < 2; qt++)
#pragma unroll
        for (int cb = 0; cb < 8; cb++)
#pragma unroll
            for (int r = 0; r < 4; r++) {
                int n = wq + qt * 16 + quad * 4 + r;
                y[(size_t)(b * N + n) * CI + cb * 16 + ln] = (f16)(O[qt][cb][r] / Osum[qt][r]);
            }
}

// ---------------- final: out[b][c][n] = W.y + Wb + x ----------------
__global__ __launch_bounds__(256) void k_final(const f16* __restrict__ y,
                                               const f16* __restrict__ Ww,
                                               const float* __restrict__ Wb,
                                               const float* __restrict__ x,
                                               float* __restrict__ out) {
    __shared__ f16 ys[64 * 136];    // [64 n][128 ci] pad 8
    __shared__ f16 Ws[128 * 136];   // [128 c][128 ci] pad 8
    int b = blockIdx.z, ch = blockIdx.y, n0 = blockIdx.x * 64;
    int tid = threadIdx.x, w = tid >> 6, lane = tid & 63, ln = lane & 15, quad = lane >> 4;
#pragma unroll
    for (int i = 0; i < 4; i++) {
        int qq = tid + i * 256; int row = qq >> 4, coff = (qq & 15) * 8;
        *(int4*)&ys[row * 136 + coff] =
            *(const int4*)&y[(size_t)(b * N + n0 + row) * CI + coff];
    }
#pragma unroll
    for (int i = 0; i < 8; i++) {
        int qq = tid + i * 256; int row = qq >> 4, coff = (qq & 15) * 8;
        *(int4*)&Ws[row * 136 + coff] =
            *(const int4*)&Ww[(size_t)(ch * 128 + row) * CI + coff];
    }
    __syncthreads();
    f32x4 acc[2][4];
#pragma unroll
    for (int rb = 0; rb < 2; rb++)
#pragma unroll
        for (int nb = 0; nb < 4; nb++) acc[rb][nb] = (f32x4){0.f, 0.f, 0.f, 0.f};
#pragma unroll
    for (int ks = 0; ks < 4; ks++) {
        half8 a0 = *(const half8*)&Ws[(w * 32 + ln) * 136 + ks * 32 + quad * 8];
        half8 a1 = *(const half8*)&Ws[(w * 32 + 16 + ln) * 136 + ks * 32 + quad * 8];
#pragma unroll
        for (int nb = 0; nb < 4; nb++) {
            half8 bf = *(const half8*)&ys[(nb * 16 + ln) * 136 + ks * 32 + quad * 8];
            acc[0][nb] = MFMA16(a0, bf, acc[0][nb]);
            acc[1][nb] = MFMA16(a1, bf, acc[1][nb]);
        }
    }
#pragma unroll
    for (int rb = 0; rb < 2; rb++) {
        int cbase = ch * 128 + w * 32 + rb * 16 + quad * 4;
#pragma unroll
        for (int nb = 0; nb < 4; nb++) {
#pragma unroll
            for (int r = 0; r < 4; r++) {
                int c = cbase + r;
                size_t addr = (size_t)(b * C + c) * N + n0 + nb * 16 + ln;
                out[addr] = acc[rb][nb][r] + Wb[c] + x[addr];
            }
        }
    }
}

extern "C" void kernel_launch(void* const* d_in, const int* in_sizes, int n_in,
                              void* d_out, int out_size, void* d_ws, size_t ws_size,
                              hipStream_t stream) {
    const float* x  = (const float*)d_in[0];
    const float* gw = (const float*)d_in[1];
    const float* gb = (const float*)d_in[2];
    const float* tw = (const float*)d_in[3];
    const float* tb = (const float*)d_in[4];
    const float* pw = (const float*)d_in[5];
    const float* pb = (const float*)d_in[6];
    const float* Ww = (const float*)d_in[7];
    const float* Wb = (const float*)d_in[8];
    float* out = (float*)d_out;
    f16* ws = (f16*)d_ws;

    f16* Q    = ws + oQ;
    f16* phiF = ws + oPF;
    f16* gF   = ws + oGF;
    f16* phiP = ws + oPP;
    f16* gPT  = ws + oGT;
    f16* Y    = ws + oPF;   // alias: phiF dead after k_pool
    f16* w16  = ws + oW;

    k_prep<<<512, 256, 0, stream>>>(tw, pw, gw, Ww, w16);
    k_projf<<<dim3(98, 8), 256, 0, stream>>>(x, w16, tb, pb, gb, Q, phiF, gF);
    k_pool<<<dim3(25, 8), 256, 0, stream>>>(phiF, gF, phiP, gPT);
    k_attn<<<dim3(98, 8), 128, 0, stream>>>(Q, phiP, gPT, Y);
    k_final<<<dim3(98, 2, 8), 256, 0, stream>>>(Y, w16 + 98304, Wb, x, out);
    (void)in_sizes; (void)n_in; (void)out_size; (void)ws_size;
}

// Round 4
// 341.228 us; speedup vs baseline: 1.3571x; 1.3571x over previous
//
#include <hip/hip_runtime.h>

typedef _Float16 f16;
typedef f16 half8 __attribute__((ext_vector_type(8)));
typedef f16 half4 __attribute__((ext_vector_type(4)));
typedef float f32x4 __attribute__((ext_vector_type(4)));

#define MFMA16(a, b, c) __builtin_amdgcn_mfma_f32_16x16x32_f16((a), (b), (c), 0, 0, 0)

static constexpr int B = 8, C = 256, CI = 128, N = 6272, M = 1568, MP = 1600;

// f16-element offsets into workspace (~45 MB). Y aliases phiF (phiF dead after k_pool).
static constexpr size_t oQ  = 0;                         // [B][N][CI]  theta
static constexpr size_t oPF = oQ  + (size_t)B * N * CI;  // [B][N][CI]  phi full-res; later Y
static constexpr size_t oGF = oPF + (size_t)B * N * CI;  // [B][N][CI]  g full-res
static constexpr size_t oPP = oGF + (size_t)B * N * CI;  // [B][MP][CI] phi pooled (K), pad zeroed
static constexpr size_t oGT = oPP + (size_t)B * MP * CI; // [B][CI][MP] g pooled transposed (V), pad zeroed
static constexpr size_t oW  = oGT + (size_t)B * MP * CI; // 4*32768 f16 weights: theta|phi|g|W

static __device__ __forceinline__ half8 hmax8(half8 a, half8 b) {
    half8 r;
#pragma unroll
    for (int j = 0; j < 8; j++) r[j] = a[j] > b[j] ? a[j] : b[j];
    return r;
}

// ---------------- weight cast fp32 -> f16 (theta|phi|g|W contiguous) ----------------
__global__ void k_prep(const float* tw, const float* pw, const float* gw,
                       const float* Ww, f16* dst) {
    int i = blockIdx.x * 256 + threadIdx.x;   // 0..131071
    int s = i >> 15, j = i & 32767;
    float v;
    if (s == 0) v = tw[j];
    else if (s == 1) v = pw[j];
    else if (s == 2) v = gw[j];
    else v = Ww[j];
    dst[i] = (f16)v;
}

// ---------------- fused 3-way projection: reads x[b][c][n] fp32 directly ----------------
__global__ __launch_bounds__(256) void k_projf(const float* __restrict__ x,
                                               const f16* __restrict__ w16,
                                               const float* __restrict__ tb,
                                               const float* __restrict__ pb,
                                               const float* __restrict__ gb,
                                               f16* __restrict__ Q,
                                               f16* __restrict__ phiF,
                                               f16* __restrict__ gF) {
    __shared__ f16 xs[64 * 72];    // [64 n][64 c] pad 8 (staged transposed + cvt)
    __shared__ f16 ws[384 * 72];   // [384 ci][64 c] pad 8
    int b = blockIdx.y, n0 = blockIdx.x * 64;
    int tid = threadIdx.x, w = tid >> 6, lane = tid & 63, ln = lane & 15, quad = lane >> 4;
    int nl = tid & 63, cg = tid >> 6;

    f32x4 acc[4][6];
#pragma unroll
    for (int nt = 0; nt < 4; nt++)
#pragma unroll
        for (int cb = 0; cb < 6; cb++) acc[nt][cb] = (f32x4){0.f, 0.f, 0.f, 0.f};

    for (int kc = 0; kc < 4; kc++) {
#pragma unroll
        for (int i = 0; i < 12; i++) {
            int qq = tid + i * 256;
            int row = qq >> 3, coff = (qq & 7) * 8;
            *(int4*)&ws[row * 72 + coff] =
                *(const int4*)&w16[(size_t)row * C + kc * 64 + coff];
        }
        {
            half8 h0, h1;
#pragma unroll
            for (int j = 0; j < 8; j++)
                h0[j] = (f16)x[(size_t)(b * C + kc * 64 + cg * 16 + j) * N + n0 + nl];
#pragma unroll
            for (int j = 0; j < 8; j++)
                h1[j] = (f16)x[(size_t)(b * C + kc * 64 + cg * 16 + 8 + j) * N + n0 + nl];
            *(half8*)&xs[nl * 72 + cg * 16] = h0;
            *(half8*)&xs[nl * 72 + cg * 16 + 8] = h1;
        }
        __syncthreads();
#pragma unroll
        for (int ks = 0; ks < 2; ks++) {
            half8 af[4];
#pragma unroll
            for (int nt = 0; nt < 4; nt++)
                af[nt] = *(const half8*)&xs[(nt * 16 + ln) * 72 + ks * 32 + quad * 8];
#pragma unroll
            for (int cb = 0; cb < 6; cb++) {
                half8 bf = *(const half8*)&ws[(w * 96 + cb * 16 + ln) * 72 + ks * 32 + quad * 8];
#pragma unroll
                for (int nt = 0; nt < 4; nt++) acc[nt][cb] = MFMA16(af[nt], bf, acc[nt][cb]);
            }
        }
        __syncthreads();
    }
#pragma unroll
    for (int cb = 0; cb < 6; cb++) {
        int cig = w * 96 + cb * 16;
        int sel = cig >> 7, cil = (cig & 127) + ln;
        const float* bp = sel == 0 ? tb : (sel == 1 ? pb : gb);
        f16* outp = sel == 0 ? Q : (sel == 1 ? phiF : gF);
        float bv = bp[cil];
#pragma unroll
        for (int nt = 0; nt < 4; nt++) {
#pragma unroll
            for (int r = 0; r < 4; r++) {
                int n = n0 + nt * 16 + quad * 4 + r;
                outp[(size_t)(b * N + n) * CI + cil] = (f16)(acc[nt][cb][r] + bv);
            }
        }
    }
}

// ---------------- 2x2 spatial maxpool; K as [m][ci], V as [ci][m] ----------------
__global__ __launch_bounds__(256) void k_pool(const f16* __restrict__ phiF, const f16* __restrict__ gF,
                                              f16* __restrict__ phiP, f16* __restrict__ gPT) {
    __shared__ f16 gt[128 * 72];   // [128 ci][64 m] pad 8
    int b = blockIdx.y, mt = blockIdx.x;   // mt 0..24 over MP=1600
    int tid = threadIdx.x;
#pragma unroll
    for (int i = 0; i < 4; i++) {
        int qq = tid + i * 256;
        int ml = qq >> 4, coff = (qq & 15) * 8;
        int m = mt * 64 + ml;
        half8 pv, gv;
        if (m < M) {
            int t = m / 196, rr = m % 196, hp = rr / 14, wp = rr % 14;
            int nb = t * 784 + hp * 56 + wp * 2;
            size_t base = ((size_t)(b * N) + nb) * CI + coff;
            half8 p0 = *(const half8*)&phiF[base];
            half8 p1 = *(const half8*)&phiF[base + CI];
            half8 p2 = *(const half8*)&phiF[base + 28 * CI];
            half8 p3 = *(const half8*)&phiF[base + 29 * CI];
            pv = hmax8(hmax8(p0, p1), hmax8(p2, p3));
            half8 g0 = *(const half8*)&gF[base];
            half8 g1 = *(const half8*)&gF[base + CI];
            half8 g2 = *(const half8*)&gF[base + 28 * CI];
            half8 g3 = *(const half8*)&gF[base + 29 * CI];
            gv = hmax8(hmax8(g0, g1), hmax8(g2, g3));
        } else {
#pragma unroll
            for (int j = 0; j < 8; j++) { pv[j] = (f16)0.f; gv[j] = (f16)0.f; }
        }
        *(half8*)&phiP[((size_t)b * MP + m) * CI + coff] = pv;
#pragma unroll
        for (int j = 0; j < 8; j++) gt[(coff + j) * 72 + ml] = gv[j];
    }
    __syncthreads();
#pragma unroll
    for (int i = 0; i < 4; i++) {
        int qq = tid + i * 256;
        int ci = qq >> 3, moff = (qq & 7) * 8;
        *(int4*)&gPT[((size_t)(b * CI) + ci) * MP + mt * 64 + moff] = *(const int4*)&gt[ci * 72 + moff];
    }
}

// ---------------- flash attention: q=256/block, 1 block/CU, S^T softmax, pipelined staging ----
__global__ __launch_bounds__(256, 1) void k_attn(const f16* __restrict__ q,
                                                 const f16* __restrict__ kk,
                                                 const f16* __restrict__ v,
                                                 f16* __restrict__ y) {
    __shared__ f16 Ks[64 * 136];     // [64 m][128 d] pad 8
    __shared__ f16 Vs[128 * 72];     // [128 ci][64 m] pad 8
    __shared__ f16 Ps[4 * 64 * 72];  // per-wave [64 q][64 m] pad 8
    int b = blockIdx.y, n0 = blockIdx.x * 256;
    int tid = threadIdx.x, w = tid >> 6, lane = tid & 63, ln = lane & 15, quad = lane >> 4;
    int wq = n0 + w * 64;
    f16* Pw = &Ps[w * 64 * 72];

    // Q fragments in registers (B-frag layout), pre-scaled by log2(e)
    half8 qf[4][4];
#pragma unroll
    for (int qt = 0; qt < 4; qt++) {
        int n = wq + qt * 16 + ln;
        if (n < N) {
#pragma unroll
            for (int ks = 0; ks < 4; ks++) {
                qf[qt][ks] = *(const half8*)&q[(size_t)(b * N + n) * CI + ks * 32 + quad * 8];
#pragma unroll
                for (int j = 0; j < 8; j++) qf[qt][ks][j] *= (f16)1.4426950408889634f;
            }
        } else {
#pragma unroll
            for (int ks = 0; ks < 4; ks++)
#pragma unroll
                for (int j = 0; j < 8; j++) qf[qt][ks][j] = (f16)0.f;
        }
    }

    f32x4 O[4][8], Osum[4];
    float mi[4];
#pragma unroll
    for (int qt = 0; qt < 4; qt++) {
        Osum[qt] = (f32x4){0.f, 0.f, 0.f, 0.f};
        mi[qt] = -1e30f;
#pragma unroll
        for (int cb = 0; cb < 8; cb++) O[qt][cb] = (f32x4){0.f, 0.f, 0.f, 0.f};
    }

    // software-pipelined staging: global loads for chunk c+1 in flight during compute of c
    int4 kreg[4], vreg[4];
#pragma unroll
    for (int i = 0; i < 4; i++) {
        int qq = tid + i * 256;
        kreg[i] = *(const int4*)&kk[((size_t)b * MP + (qq >> 4)) * CI + (qq & 15) * 8];
        vreg[i] = *(const int4*)&v[((size_t)(b * CI) + (qq >> 3)) * MP + (qq & 7) * 8];
    }

    for (int mc = 0; mc < 25; mc++) {
#pragma unroll
        for (int i = 0; i < 4; i++) {
            int qq = tid + i * 256;
            *(int4*)&Ks[(qq >> 4) * 136 + (qq & 15) * 8] = kreg[i];
            *(int4*)&Vs[(qq >> 3) * 72 + (qq & 7) * 8] = vreg[i];
        }
        if (mc + 1 < 25) {
#pragma unroll
            for (int i = 0; i < 4; i++) {
                int qq = tid + i * 256;
                kreg[i] = *(const int4*)&kk[((size_t)b * MP + (mc + 1) * 64 + (qq >> 4)) * CI + (qq & 15) * 8];
                vreg[i] = *(const int4*)&v[((size_t)(b * CI) + (qq >> 3)) * MP + (mc + 1) * 64 + (qq & 7) * 8];
            }
        }
        __syncthreads();

        // ---- S^T = MFMA(K, Q): rows m = quad*4+r (+16mt), cols q = ln (+16qt) ----
        f32x4 S[4][4];
#pragma unroll
        for (int mt = 0; mt < 4; mt++)
#pragma unroll
            for (int qt = 0; qt < 4; qt++) S[mt][qt] = (f32x4){0.f, 0.f, 0.f, 0.f};
#pragma unroll
        for (int ks = 0; ks < 4; ks++) {
            half8 kb[4];
#pragma unroll
            for (int mt = 0; mt < 4; mt++)
                kb[mt] = *(const half8*)&Ks[(mt * 16 + ln) * 136 + ks * 32 + quad * 8];
#pragma unroll
            for (int mt = 0; mt < 4; mt++)
#pragma unroll
                for (int qt = 0; qt < 4; qt++)
                    S[mt][qt] = MFMA16(kb[mt], qf[qt][ks], S[mt][qt]);
        }

        // ---- online softmax in S^T domain (q = lane ln) ----
#pragma unroll
        for (int qt = 0; qt < 4; qt++) {
            float cm = S[0][qt][0];
#pragma unroll
            for (int mt = 0; mt < 4; mt++)
#pragma unroll
                for (int r = 0; r < 4; r++) cm = fmaxf(cm, S[mt][qt][r]);
            cm = fmaxf(cm, __shfl_xor(cm, 16));
            cm = fmaxf(cm, __shfl_xor(cm, 32));
            float mnew = fmaxf(mi[qt], cm);
            float alpha = __builtin_amdgcn_exp2f(mi[qt] - mnew);
            mi[qt] = mnew;
#pragma unroll
            for (int mt = 0; mt < 4; mt++) {
                half4 ph;
#pragma unroll
                for (int r = 0; r < 4; r++)
                    ph[r] = (f16)__builtin_amdgcn_exp2f(S[mt][qt][r] - mnew);
                *(half4*)&Pw[(qt * 16 + ln) * 72 + mt * 16 + quad * 4] = ph;
            }
            // alpha lives at lane ln=q; O rows are q=quad*4+r — transpose via shuffle
            f32x4 aO;
#pragma unroll
            for (int r = 0; r < 4; r++) aO[r] = __shfl(alpha, quad * 4 + r, 16);
#pragma unroll
            for (int cb = 0; cb < 8; cb++) O[qt][cb] *= aO;
            Osum[qt] *= aO;
        }

        // ---- PV + ones-column rowsum (P private per wave: no barrier needed) ----
#pragma unroll
        for (int ks2 = 0; ks2 < 2; ks2++) {
            half8 ap[4];
#pragma unroll
            for (int qt = 0; qt < 4; qt++)
                ap[qt] = *(const half8*)&Pw[(qt * 16 + ln) * 72 + ks2 * 32 + quad * 8];
            f16 ov = (mc * 64 + ks2 * 32 < M) ? (f16)1.0f : (f16)0.0f;
            half8 on;
#pragma unroll
            for (int j = 0; j < 8; j++) on[j] = ov;
#pragma unroll
            for (int cb = 0; cb < 8; cb++) {
                half8 bv = *(const half8*)&Vs[(cb * 16 + ln) * 72 + ks2 * 32 + quad * 8];
#pragma unroll
                for (int qt = 0; qt < 4; qt++) O[qt][cb] = MFMA16(ap[qt], bv, O[qt][cb]);
            }
#pragma unroll
            for (int qt = 0; qt < 4; qt++) Osum[qt] = MFMA16(ap[qt], on, Osum[qt]);
        }
        __syncthreads();
    }

#pragma unroll
    for (int qt = 0; qt < 4; qt++)
#pragma unroll
        for (int cb = 0; cb < 8; cb++)
#pragma unroll
            for (int r = 0; r < 4; r++) {
                int n = wq + qt * 16 + quad * 4 + r;
                if (n < N)
                    y[(size_t)(b * N + n) * CI + cb * 16 + ln] = (f16)(O[qt][cb][r] / Osum[qt][r]);
            }
}

// ---------------- final: out[b][c][n] = W.y + Wb + x ----------------
__global__ __launch_bounds__(256) void k_final(const f16* __restrict__ y,
                                               const f16* __restrict__ Ww,
                                               const float* __restrict__ Wb,
                                               const float* __restrict__ x,
                                               float* __restrict__ out) {
    __shared__ f16 ys[64 * 136];    // [64 n][128 ci] pad 8
    __shared__ f16 Ws[128 * 136];   // [128 c][128 ci] pad 8
    int b = blockIdx.z, ch = blockIdx.y, n0 = blockIdx.x * 64;
    int tid = threadIdx.x, w = tid >> 6, lane = tid & 63, ln = lane & 15, quad = lane >> 4;
#pragma unroll
    for (int i = 0; i < 4; i++) {
        int qq = tid + i * 256; int row = qq >> 4, coff = (qq & 15) * 8;
        *(int4*)&ys[row * 136 + coff] =
            *(const int4*)&y[(size_t)(b * N + n0 + row) * CI + coff];
    }
#pragma unroll
    for (int i = 0; i < 8; i++) {
        int qq = tid + i * 256; int row = qq >> 4, coff = (qq & 15) * 8;
        *(int4*)&Ws[row * 136 + coff] =
            *(const int4*)&Ww[(size_t)(ch * 128 + row) * CI + coff];
    }
    __syncthreads();
    f32x4 acc[2][4];
#pragma unroll
    for (int rb = 0; rb < 2; rb++)
#pragma unroll
        for (int nb = 0; nb < 4; nb++) acc[rb][nb] = (f32x4){0.f, 0.f, 0.f, 0.f};
#pragma unroll
    for (int ks = 0; ks < 4; ks++) {
        half8 a0 = *(const half8*)&Ws[(w * 32 + ln) * 136 + ks * 32 + quad * 8];
        half8 a1 = *(const half8*)&Ws[(w * 32 + 16 + ln) * 136 + ks * 32 + quad * 8];
#pragma unroll
        for (int nb = 0; nb < 4; nb++) {
            half8 bf = *(const half8*)&ys[(nb * 16 + ln) * 136 + ks * 32 + quad * 8];
            acc[0][nb] = MFMA16(a0, bf, acc[0][nb]);
            acc[1][nb] = MFMA16(a1, bf, acc[1][nb]);
        }
    }
#pragma unroll
    for (int rb = 0; rb < 2; rb++) {
        int cbase = ch * 128 + w * 32 + rb * 16 + quad * 4;
#pragma unroll
        for (int nb = 0; nb < 4; nb++) {
#pragma unroll
            for (int r = 0; r < 4; r++) {
                int c = cbase + r;
                size_t addr = (size_t)(b * C + c) * N + n0 + nb * 16 + ln;
                out[addr] = acc[rb][nb][r] + Wb[c] + x[addr];
            }
        }
    }
}

extern "C" void kernel_launch(void* const* d_in, const int* in_sizes, int n_in,
                              void* d_out, int out_size, void* d_ws, size_t ws_size,
                              hipStream_t stream) {
    const float* x  = (const float*)d_in[0];
    const float* gw = (const float*)d_in[1];
    const float* gb = (const float*)d_in[2];
    const float* tw = (const float*)d_in[3];
    const float* tb = (const float*)d_in[4];
    const float* pw = (const float*)d_in[5];
    const float* pb = (const float*)d_in[6];
    const float* Ww = (const float*)d_in[7];
    const float* Wb = (const float*)d_in[8];
    float* out = (float*)d_out;
    f16* ws = (f16*)d_ws;

    f16* Q    = ws + oQ;
    f16* phiF = ws + oPF;
    f16* gF   = ws + oGF;
    f16* phiP = ws + oPP;
    f16* gPT  = ws + oGT;
    f16* Y    = ws + oPF;   // alias: phiF dead after k_pool
    f16* w16  = ws + oW;

    k_prep<<<512, 256, 0, stream>>>(tw, pw, gw, Ww, w16);
    k_projf<<<dim3(98, 8), 256, 0, stream>>>(x, w16, tb, pb, gb, Q, phiF, gF);
    k_pool<<<dim3(25, 8), 256, 0, stream>>>(phiF, gF, phiP, gPT);
    k_attn<<<dim3(25, 8), 256, 0, stream>>>(Q, phiP, gPT, Y);
    k_final<<<dim3(98, 2, 8), 256, 0, stream>>>(Y, w16 + 98304, Wb, x, out);
    (void)in_sizes; (void)n_in; (void)out_size; (void)ws_size;
}

// Round 5
// 297.459 us; speedup vs baseline: 1.5568x; 1.1471x over previous
//
#include <hip/hip_runtime.h>

typedef _Float16 f16;
typedef f16 half8 __attribute__((ext_vector_type(8)));
typedef f16 half4 __attribute__((ext_vector_type(4)));
typedef float f32x4 __attribute__((ext_vector_type(4)));
typedef float f32x16 __attribute__((ext_vector_type(16)));

#define MFMA16(a, b, c) __builtin_amdgcn_mfma_f32_16x16x32_f16((a), (b), (c), 0, 0, 0)
#define MFMA32(a, b, c) __builtin_amdgcn_mfma_f32_32x32x16_f16((a), (b), (c), 0, 0, 0)

static constexpr int B = 8, C = 256, CI = 128, N = 6272, M = 1568, MP = 1600;

// f16-element offsets into workspace (~45 MB). Y aliases phiF (phiF dead after k_pool).
static constexpr size_t oQ  = 0;                         // [B][N][CI]  theta
static constexpr size_t oPF = oQ  + (size_t)B * N * CI;  // [B][N][CI]  phi full-res; later Y
static constexpr size_t oGF = oPF + (size_t)B * N * CI;  // [B][N][CI]  g full-res
static constexpr size_t oPP = oGF + (size_t)B * N * CI;  // [B][MP][CI] phi pooled (K), pad zeroed
static constexpr size_t oGT = oPP + (size_t)B * MP * CI; // [B][CI][MP] g pooled, transposed, σ-permuted m
static constexpr size_t oW  = oGT + (size_t)B * MP * CI; // 4*32768 f16 weights: theta|phi|g|W

static __device__ __forceinline__ half8 hmax8(half8 a, half8 b) {
    half8 r;
#pragma unroll
    for (int j = 0; j < 8; j++) r[j] = a[j] > b[j] ? a[j] : b[j];
    return r;
}

// ---------------- weight cast fp32 -> f16 (theta|phi|g|W contiguous) ----------------
__global__ void k_prep(const float* tw, const float* pw, const float* gw,
                       const float* Ww, f16* dst) {
    int i = blockIdx.x * 256 + threadIdx.x;   // 0..131071
    int s = i >> 15, j = i & 32767;
    float v;
    if (s == 0) v = tw[j];
    else if (s == 1) v = pw[j];
    else if (s == 2) v = gw[j];
    else v = Ww[j];
    dst[i] = (f16)v;
}

// ---------------- fused 3-way projection: reads x[b][c][n] fp32 directly ----------------
__global__ __launch_bounds__(256) void k_projf(const float* __restrict__ x,
                                               const f16* __restrict__ w16,
                                               const float* __restrict__ tb,
                                               const float* __restrict__ pb,
                                               const float* __restrict__ gb,
                                               f16* __restrict__ Q,
                                               f16* __restrict__ phiF,
                                               f16* __restrict__ gF) {
    __shared__ f16 xs[64 * 72];    // [64 n][64 c] pad 8 (staged transposed + cvt)
    __shared__ f16 ws[384 * 72];   // [384 ci][64 c] pad 8
    int b = blockIdx.y, n0 = blockIdx.x * 64;
    int tid = threadIdx.x, w = tid >> 6, lane = tid & 63, ln = lane & 15, quad = lane >> 4;
    int nl = tid & 63, cg = tid >> 6;

    f32x4 acc[4][6];
#pragma unroll
    for (int nt = 0; nt < 4; nt++)
#pragma unroll
        for (int cb = 0; cb < 6; cb++) acc[nt][cb] = (f32x4){0.f, 0.f, 0.f, 0.f};

    for (int kc = 0; kc < 4; kc++) {
#pragma unroll
        for (int i = 0; i < 12; i++) {
            int qq = tid + i * 256;
            int row = qq >> 3, coff = (qq & 7) * 8;
            *(int4*)&ws[row * 72 + coff] =
                *(const int4*)&w16[(size_t)row * C + kc * 64 + coff];
        }
        {
            half8 h0, h1;
#pragma unroll
            for (int j = 0; j < 8; j++)
                h0[j] = (f16)x[(size_t)(b * C + kc * 64 + cg * 16 + j) * N + n0 + nl];
#pragma unroll
            for (int j = 0; j < 8; j++)
                h1[j] = (f16)x[(size_t)(b * C + kc * 64 + cg * 16 + 8 + j) * N + n0 + nl];
            *(half8*)&xs[nl * 72 + cg * 16] = h0;
            *(half8*)&xs[nl * 72 + cg * 16 + 8] = h1;
        }
        __syncthreads();
#pragma unroll
        for (int ks = 0; ks < 2; ks++) {
            half8 af[4];
#pragma unroll
            for (int nt = 0; nt < 4; nt++)
                af[nt] = *(const half8*)&xs[(nt * 16 + ln) * 72 + ks * 32 + quad * 8];
#pragma unroll
            for (int cb = 0; cb < 6; cb++) {
                half8 bf = *(const half8*)&ws[(w * 96 + cb * 16 + ln) * 72 + ks * 32 + quad * 8];
#pragma unroll
                for (int nt = 0; nt < 4; nt++) acc[nt][cb] = MFMA16(af[nt], bf, acc[nt][cb]);
            }
        }
        __syncthreads();
    }
#pragma unroll
    for (int cb = 0; cb < 6; cb++) {
        int cig = w * 96 + cb * 16;
        int sel = cig >> 7, cil = (cig & 127) + ln;
        const float* bp = sel == 0 ? tb : (sel == 1 ? pb : gb);
        f16* outp = sel == 0 ? Q : (sel == 1 ? phiF : gF);
        float bv = bp[cil];
#pragma unroll
        for (int nt = 0; nt < 4; nt++) {
#pragma unroll
            for (int r = 0; r < 4; r++) {
                int n = n0 + nt * 16 + quad * 4 + r;
                outp[(size_t)(b * N + n) * CI + cil] = (f16)(acc[nt][cb][r] + bv);
            }
        }
    }
}

// ---------------- 2x2 maxpool; K as [m][ci]; V as [ci][mσ] (σ = swap bits 2,3 of m) ----------------
__global__ __launch_bounds__(256) void k_pool(const f16* __restrict__ phiF, const f16* __restrict__ gF,
                                              f16* __restrict__ phiP, f16* __restrict__ gPT) {
    __shared__ f16 gt[128 * 72];   // [128 ci][64 mσ] pad 8
    int b = blockIdx.y, mt = blockIdx.x;   // mt 0..24 over MP=1600
    int tid = threadIdx.x;
#pragma unroll
    for (int i = 0; i < 4; i++) {
        int qq = tid + i * 256;
        int ml = qq >> 4, coff = (qq & 15) * 8;
        int m = mt * 64 + ml;
        half8 pv, gv;
        if (m < M) {
            int t = m / 196, rr = m % 196, hp = rr / 14, wp = rr % 14;
            int nb = t * 784 + hp * 56 + wp * 2;
            size_t base = ((size_t)(b * N) + nb) * CI + coff;
            half8 p0 = *(const half8*)&phiF[base];
            half8 p1 = *(const half8*)&phiF[base + CI];
            half8 p2 = *(const half8*)&phiF[base + 28 * CI];
            half8 p3 = *(const half8*)&phiF[base + 29 * CI];
            pv = hmax8(hmax8(p0, p1), hmax8(p2, p3));
            half8 g0 = *(const half8*)&gF[base];
            half8 g1 = *(const half8*)&gF[base + CI];
            half8 g2 = *(const half8*)&gF[base + 28 * CI];
            half8 g3 = *(const half8*)&gF[base + 29 * CI];
            gv = hmax8(hmax8(g0, g1), hmax8(g2, g3));
        } else {
#pragma unroll
            for (int j = 0; j < 8; j++) { pv[j] = (f16)0.f; gv[j] = (f16)0.f; }
        }
        *(half8*)&phiP[((size_t)b * MP + m) * CI + coff] = pv;
        int mls = (ml & 51) | ((ml & 4) << 1) | ((ml & 8) >> 1);   // σ: swap bits 2,3
#pragma unroll
        for (int j = 0; j < 8; j++) gt[(coff + j) * 72 + mls] = gv[j];
    }
    __syncthreads();
#pragma unroll
    for (int i = 0; i < 4; i++) {
        int qq = tid + i * 256;
        int ci = qq >> 3, moff = (qq & 7) * 8;
        *(int4*)&gPT[((size_t)(b * CI) + ci) * MP + mt * 64 + moff] = *(const int4*)&gt[ci * 72 + moff];
    }
}

// ---------------- flash attention: 32x32x16 MFMA, S^T layout, per-lane softmax, no P buffer ----
__global__ __launch_bounds__(256, 2) void k_attn(const f16* __restrict__ q,
                                                 const f16* __restrict__ kk,
                                                 const f16* __restrict__ v,
                                                 f16* __restrict__ y) {
    __shared__ f16 Ks[64 * 136];   // [64 m][128 ci] pad 8
    __shared__ f16 Vs[128 * 72];   // [128 ci][64 mσ] pad 8
    int b = blockIdx.y, n0 = blockIdx.x * 128;
    int tid = threadIdx.x, w = tid >> 6, lane = tid & 63;
    int l31 = lane & 31, h = lane >> 5;
    int wq = n0 + w * 32;

    // Q B-frags in regs (col=q=l31, k=ci), scaled by log2e
    half8 qf[8];
#pragma unroll
    for (int kb = 0; kb < 8; kb++) {
        qf[kb] = *(const half8*)&q[(size_t)(b * N + wq + l31) * CI + kb * 16 + h * 8];
#pragma unroll
        for (int j = 0; j < 8; j++) qf[kb][j] *= (f16)1.4426950408889634f;
    }

    f32x16 O[4];
#pragma unroll
    for (int cb = 0; cb < 4; cb++)
#pragma unroll
        for (int r = 0; r < 16; r++) O[cb][r] = 0.f;
    float mi = -1e30f, li = 0.f;

    // prefetch chunk 0 into regs
    int4 kreg[4], vreg[4];
#pragma unroll
    for (int i = 0; i < 4; i++) {
        int qq = tid + i * 256;
        kreg[i] = *(const int4*)&kk[((size_t)b * MP + (qq >> 4)) * CI + (qq & 15) * 8];
        vreg[i] = *(const int4*)&v[((size_t)(b * CI) + (qq >> 3)) * MP + (qq & 7) * 8];
    }

    for (int mc = 0; mc < 25; mc++) {
#pragma unroll
        for (int i = 0; i < 4; i++) {
            int qq = tid + i * 256;
            *(int4*)&Ks[(qq >> 4) * 136 + (qq & 15) * 8] = kreg[i];
            *(int4*)&Vs[(qq >> 3) * 72 + (qq & 7) * 8] = vreg[i];
        }
        if (mc + 1 < 25) {
#pragma unroll
            for (int i = 0; i < 4; i++) {
                int qq = tid + i * 256;
                kreg[i] = *(const int4*)&kk[((size_t)b * MP + (mc + 1) * 64 + (qq >> 4)) * CI + (qq & 15) * 8];
                vreg[i] = *(const int4*)&v[((size_t)(b * CI) + (qq >> 3)) * MP + (mc + 1) * 64 + (qq & 7) * 8];
            }
        }
        __syncthreads();

        // ---- S^T = MFMA(A=K, B=Q): col=q=l31, rows m = 32mt + (r&3)+8(r>>2)+4h ----
        f32x16 S0, S1;
#pragma unroll
        for (int r = 0; r < 16; r++) { S0[r] = 0.f; S1[r] = 0.f; }
#pragma unroll
        for (int kb = 0; kb < 8; kb++) {
            half8 a0 = *(const half8*)&Ks[l31 * 136 + kb * 16 + h * 8];
            half8 a1 = *(const half8*)&Ks[(32 + l31) * 136 + kb * 16 + h * 8];
            S0 = MFMA32(a0, qf[kb], S0);
            S1 = MFMA32(a1, qf[kb], S1);
        }
        if (mc == 24) {     // m in [1568,1600) = all of mt=1 tile: mask pad
#pragma unroll
            for (int r = 0; r < 16; r++) S1[r] = -3.0e38f;
        }

        // ---- per-lane online softmax (col q = l31; halves h combine via xor32) ----
        float cm = S0[0];
#pragma unroll
        for (int r = 0; r < 16; r++) { cm = fmaxf(cm, S0[r]); cm = fmaxf(cm, S1[r]); }
        cm = fmaxf(cm, __shfl_xor(cm, 32));
        float mnew = fmaxf(mi, cm);
        float alpha = __builtin_amdgcn_exp2f(mi - mnew);
        mi = mnew;
        float rs = 0.f;
        half8 P[4];
#pragma unroll
        for (int r = 0; r < 16; r++) {
            float p0 = __builtin_amdgcn_exp2f(S0[r] - mnew);
            float p1 = __builtin_amdgcn_exp2f(S1[r] - mnew);
            rs += p0 + p1;
            P[r >> 3][r & 7] = (f16)p0;
            P[2 + (r >> 3)][r & 7] = (f16)p1;
        }
        rs += __shfl_xor(rs, 32);
        li = li * alpha + rs;
#pragma unroll
        for (int cb = 0; cb < 4; cb++)
#pragma unroll
            for (int r = 0; r < 16; r++) O[cb][r] *= alpha;

        // ---- O^T += MFMA(A=Vσ, B=Pσ): rows ci, col q=l31 ----
#pragma unroll
        for (int kb = 0; kb < 4; kb++) {
#pragma unroll
            for (int cb = 0; cb < 4; cb++) {
                half8 a = *(const half8*)&Vs[(cb * 32 + l31) * 72 + kb * 16 + h * 8];
                O[cb] = MFMA32(a, P[kb], O[cb]);
            }
        }
        __syncthreads();
    }

    // ---- epilogue: y[n=q][ci] = O^T / li (everything per-lane) ----
    float inv = 1.f / li;
#pragma unroll
    for (int cb = 0; cb < 4; cb++)
#pragma unroll
        for (int g = 0; g < 4; g++) {
            half4 o4;
#pragma unroll
            for (int r = 0; r < 4; r++) o4[r] = (f16)(O[cb][g * 4 + r] * inv);
            int ci = cb * 32 + g * 8 + h * 4;
            *(half4*)&y[(size_t)(b * N + wq + l31) * CI + ci] = o4;
        }
}

// ---------------- final: out[b][c][n] = W.y + Wb + x ----------------
__global__ __launch_bounds__(256) void k_final(const f16* __restrict__ y,
                                               const f16* __restrict__ Ww,
                                               const float* __restrict__ Wb,
                                               const float* __restrict__ x,
                                               float* __restrict__ out) {
    __shared__ f16 ys[64 * 136];    // [64 n][128 ci] pad 8
    __shared__ f16 Ws[128 * 136];   // [128 c][128 ci] pad 8
    int b = blockIdx.z, ch = blockIdx.y, n0 = blockIdx.x * 64;
    int tid = threadIdx.x, w = tid >> 6, lane = tid & 63, ln = lane & 15, quad = lane >> 4;
#pragma unroll
    for (int i = 0; i < 4; i++) {
        int qq = tid + i * 256; int row = qq >> 4, coff = (qq & 15) * 8;
        *(int4*)&ys[row * 136 + coff] =
            *(const int4*)&y[(size_t)(b * N + n0 + row) * CI + coff];
    }
#pragma unroll
    for (int i = 0; i < 8; i++) {
        int qq = tid + i * 256; int row = qq >> 4, coff = (qq & 15) * 8;
        *(int4*)&Ws[row * 136 + coff] =
            *(const int4*)&Ww[(size_t)(ch * 128 + row) * CI + coff];
    }
    __syncthreads();
    f32x4 acc[2][4];
#pragma unroll
    for (int rb = 0; rb < 2; rb++)
#pragma unroll
        for (int nb = 0; nb < 4; nb++) acc[rb][nb] = (f32x4){0.f, 0.f, 0.f, 0.f};
#pragma unroll
    for (int ks = 0; ks < 4; ks++) {
        half8 a0 = *(const half8*)&Ws[(w * 32 + ln) * 136 + ks * 32 + quad * 8];
        half8 a1 = *(const half8*)&Ws[(w * 32 + 16 + ln) * 136 + ks * 32 + quad * 8];
#pragma unroll
        for (int nb = 0; nb < 4; nb++) {
            half8 bf = *(const half8*)&ys[(nb * 16 + ln) * 136 + ks * 32 + quad * 8];
            acc[0][nb] = MFMA16(a0, bf, acc[0][nb]);
            acc[1][nb] = MFMA16(a1, bf, acc[1][nb]);
        }
    }
#pragma unroll
    for (int rb = 0; rb < 2; rb++) {
        int cbase = ch * 128 + w * 32 + rb * 16 + quad * 4;
#pragma unroll
        for (int nb = 0; nb < 4; nb++) {
#pragma unroll
            for (int r = 0; r < 4; r++) {
                int c = cbase + r;
                size_t addr = (size_t)(b * C + c) * N + n0 + nb * 16 + ln;
                out[addr] = acc[rb][nb][r] + Wb[c] + x[addr];
            }
        }
    }
}

extern "C" void kernel_launch(void* const* d_in, const int* in_sizes, int n_in,
                              void* d_out, int out_size, void* d_ws, size_t ws_size,
                              hipStream_t stream) {
    const float* x  = (const float*)d_in[0];
    const float* gw = (const float*)d_in[1];
    const float* gb = (const float*)d_in[2];
    const float* tw = (const float*)d_in[3];
    const float* tb = (const float*)d_in[4];
    const float* pw = (const float*)d_in[5];
    const float* pb = (const float*)d_in[6];
    const float* Ww = (const float*)d_in[7];
    const float* Wb = (const float*)d_in[8];
    float* out = (float*)d_out;
    f16* ws = (f16*)d_ws;

    f16* Q    = ws + oQ;
    f16* phiF = ws + oPF;
    f16* gF   = ws + oGF;
    f16* phiP = ws + oPP;
    f16* gPT  = ws + oGT;
    f16* Y    = ws + oPF;   // alias: phiF dead after k_pool
    f16* w16  = ws + oW;

    k_prep<<<512, 256, 0, stream>>>(tw, pw, gw, Ww, w16);
    k_projf<<<dim3(98, 8), 256, 0, stream>>>(x, w16, tb, pb, gb, Q, phiF, gF);
    k_pool<<<dim3(25, 8), 256, 0, stream>>>(phiF, gF, phiP, gPT);
    k_attn<<<dim3(49, 8), 256, 0, stream>>>(Q, phiP, gPT, Y);
    k_final<<<dim3(98, 2, 8), 256, 0, stream>>>(Y, w16 + 98304, Wb, x, out);
    (void)in_sizes; (void)n_in; (void)out_size; (void)ws_size;
}